// Round 11
// baseline (102.365 us; speedup 1.0000x reference)
//
#include <hip/hip_runtime.h>

#define DIM       128
#define BATCH     16384
#define RELN      500
#define ALPHA     0.001f
#define CHUNK     8
#define MAXCHUNKS (BATCH / CHUNK + RELN)   // 2548 chunk slots (padded)
#define NHB       64                       // hist/scatter blocks (256 elems each)

__device__ __forceinline__ float dot4(float4 a, float4 b) {
    return a.x * b.x + a.y * b.y + a.z * b.z + a.w * b.w;
}

// ---------- K1: own-slice histogram -> BIN-MAJOR partials ----------
__global__ void __launch_bounds__(256) hist_kernel(
    const int* __restrict__ r_idx,
    int*       __restrict__ partialT)    // [512][NHB] bin-major
{
    __shared__ int cnt[512];
    const int tid = threadIdx.x;
    cnt[tid] = 0; cnt[tid + 256] = 0;
    __syncthreads();
    atomicAdd(&cnt[r_idx[blockIdx.x * 256 + tid]], 1);
    __syncthreads();
    partialT[tid * NHB + blockIdx.x]         = cnt[tid];
    partialT[(tid + 256) * NHB + blockIdx.x] = cnt[tid + 256];
}

// ---------- K2: scatter (redundant per-block scan, all LDS/regs) ----------
// Each block: reads the bin-major partial rows (contiguous 256 B per bin,
// thread owns bins tid and tid+256), computes global totals + prefix for its
// own bid in registers, 512-wide LDS scan -> excl, then scatters its own 256
// elements with LDS-rank atomics. Block NHB-1 additionally builds chunk_info
// and zeroes the done counter. No global atomics, no serial strided chains.
__global__ void __launch_bounds__(256) scatter_kernel(
    const int*   __restrict__ r_idx,
    const int*   __restrict__ h_idx,
    const int*   __restrict__ t_idx,
    const float* __restrict__ labels,
    const int*   __restrict__ partialT,   // [512][NHB]
    int4*        __restrict__ quad,       // [BATCH] (h, t, b, label_bits)
    int4*        __restrict__ chunk_info, // [MAXCHUNKS] (rel, start, e_cnt, 0)
    int*         __restrict__ done)       // [1] zeroed here
{
    __shared__ int sc[512];
    __shared__ int boff[512];
    __shared__ int lcnt[512];
    const int tid = threadIdx.x;
    const int bid = blockIdx.x;

    // per-bin total + prefix(b < bid), contiguous int4 reads
    const int4* row0 = (const int4*)(partialT + tid * NHB);
    const int4* row1 = (const int4*)(partialT + (tid + 256) * NHB);
    int tot0 = 0, pre0 = 0, tot1 = 0, pre1 = 0;
    #pragma unroll
    for (int k = 0; k < 16; ++k) {
        const int4 v0 = row0[k];
        const int4 v1 = row1[k];
        tot0 += v0.x + v0.y + v0.z + v0.w;
        tot1 += v1.x + v1.y + v1.z + v1.w;
        const int b = 4 * k;
        pre0 += (b < bid ? v0.x : 0) + (b + 1 < bid ? v0.y : 0)
              + (b + 2 < bid ? v0.z : 0) + (b + 3 < bid ? v0.w : 0);
        pre1 += (b < bid ? v1.x : 0) + (b + 1 < bid ? v1.y : 0)
              + (b + 2 < bid ? v1.z : 0) + (b + 3 < bid ? v1.w : 0);
    }

    // 512-wide inclusive scan (2 elems/thread Hillis-Steele)
    sc[tid] = tot0; sc[tid + 256] = tot1;
    __syncthreads();
    for (int d = 1; d < 512; d <<= 1) {
        const int x0 = (tid >= d) ? sc[tid - d] : 0;
        const int x1 = (tid + 256 >= d) ? sc[tid + 256 - d] : 0;
        __syncthreads();
        sc[tid] += x0; sc[tid + 256] += x1;
        __syncthreads();
    }
    const int excl0 = sc[tid] - tot0;
    const int excl1 = sc[tid + 256] - tot1;
    boff[tid]       = excl0 + pre0;
    boff[tid + 256] = excl1 + pre1;
    lcnt[tid] = 0; lcnt[tid + 256] = 0;
    __syncthreads();

    // scatter own element
    {
        const int i   = bid * 256 + tid;
        const int r   = r_idx[i];
        const int pos = boff[r] + atomicAdd(&lcnt[r], 1);
        quad[pos] = make_int4(h_idx[i], t_idx[i], i, __float_as_int(labels[i]));
    }

    // block NHB-1: chunk_info (+ zero tail) + done=0  (uniform branch)
    if (bid == NHB - 1) {
        const int nc0 = (tot0 + CHUNK - 1) / CHUNK;            // bins 0..255 < RELN
        const int nc1 = (tid + 256 < RELN) ? (tot1 + CHUNK - 1) / CHUNK : 0;
        __syncthreads();
        sc[tid] = nc0; sc[tid + 256] = nc1;
        __syncthreads();
        for (int d = 1; d < 512; d <<= 1) {
            const int x0 = (tid >= d) ? sc[tid - d] : 0;
            const int x1 = (tid + 256 >= d) ? sc[tid + 256 - d] : 0;
            __syncthreads();
            sc[tid] += x0; sc[tid + 256] += x1;
            __syncthreads();
        }
        const int cb0   = sc[tid] - nc0;
        const int cb1   = sc[tid + 256] - nc1;
        const int total = sc[511];
        for (int i = 0; i < nc0; ++i)
            chunk_info[cb0 + i] = make_int4(tid, excl0 + i * CHUNK,
                                            min(CHUNK, tot0 - i * CHUNK), 0);
        for (int i = 0; i < nc1; ++i)
            chunk_info[cb1 + i] = make_int4(tid + 256, excl1 + i * CHUNK,
                                            min(CHUNK, tot1 - i * CHUNK), 0);
        for (int p = total + tid; p < MAXCHUNKS; p += 256)
            chunk_info[p] = make_int4(0, 0, 0, 0);
        if (tid == 0) done[0] = 0;
    }
}

// ---------- K3: main + fused last-block loss reduction ----------
__global__ void __launch_bounds__(256) rescal_main_kernel(
    const int4*  __restrict__ chunk_info,
    const int4*  __restrict__ quad,
    const float* __restrict__ ent_w,
    const float* __restrict__ rel_w,
    float*       __restrict__ out,          // [0]=loss, [1..BATCH]=scores
    float4*      __restrict__ chunk_out,    // [MAXCHUNKS] (errS, htS, cnt*r2, 0)
    int*         __restrict__ done)
{
    // bijective XCD swizzle: consecutive cids (same relation) share an XCD L2
    const int bid = blockIdx.x;
    const int xcd = bid & 7;
    const int j   = bid >> 3;
    const int q   = MAXCHUNKS / 8;
    const int r_  = MAXCHUNKS % 8;
    const int cid = (xcd < r_ ? xcd * (q + 1) : r_ * (q + 1) + (xcd - r_) * q) + j;

    const int tid = threadIdx.x;

    __shared__ float t_lds[CHUNK][DIM];
    __shared__ float h_lds[CHUNK][DIM];
    __shared__ float red[4][CHUNK];
    __shared__ float ht_red[CHUNK];
    __shared__ float d2s[CHUNK];
    __shared__ float r2_red[4];
    __shared__ int   amlast;

    const int4 ci    = chunk_info[cid];
    const int  rel   = ci.x;
    const int  start = ci.y;
    const int  e_cnt = ci.z;

    if (e_cnt == 0) {
        if (tid == 0) chunk_out[cid] = make_float4(0.f, 0.f, 0.f, 0.f);
    } else {
        const int w   = tid >> 6;
        const int l   = tid & 63;
        const int hi  = l >> 5;
        const int c4  = l & 31;
        const int rbase = 32 * w + 16 * hi;

        // stage t, h (32 threads per element, 1 float4 each)
        const int eg   = tid >> 5;
        const int col4 = tid & 31;
        float4 tv4 = make_float4(0.f, 0.f, 0.f, 0.f);
        float4 hv4 = tv4;
        if (eg < e_cnt) {
            const int4 qd = quad[start + eg];
            hv4 = *(const float4*)(ent_w + (size_t)qd.x * DIM + col4 * 4);
            tv4 = *(const float4*)(ent_w + (size_t)qd.y * DIM + col4 * 4);
        }
        *(float4*)&t_lds[eg][col4 * 4] = tv4;
        *(float4*)&h_lds[eg][col4 * 4] = hv4;

        float htp = dot4(tv4, tv4) + dot4(hv4, hv4);
        #pragma unroll
        for (int off = 16; off >= 1; off >>= 1) htp += __shfl_xor(htp, off);
        if ((tid & 31) == 0) ht_red[eg] = htp;
        __syncthreads();

        // t fragments to registers (b128, conflict-free)
        float4 t4[CHUNK];
        #pragma unroll
        for (int e = 0; e < CHUNK; ++e)
            t4[e] = *(const float4*)&t_lds[e][c4 * 4];

        // stream R in 4-row groups (only 16 R-regs live)
        const float4* Rb = (const float4*)(rel_w + (size_t)rel * (DIM * DIM)
                                                 + (size_t)rbase * DIM) + c4;
        float acc[CHUNK];
        #pragma unroll
        for (int e = 0; e < CHUNK; ++e) acc[e] = 0.f;
        float r2 = 0.f;

        #pragma unroll 1
        for (int pg = 0; pg < 4; ++pg) {
            const float4 r0 = Rb[(4 * pg + 0) * (DIM / 4)];
            const float4 r1 = Rb[(4 * pg + 1) * (DIM / 4)];
            const float4 rq = Rb[(4 * pg + 2) * (DIM / 4)];
            const float4 r3 = Rb[(4 * pg + 3) * (DIM / 4)];
            r2 += dot4(r0, r0) + dot4(r1, r1) + dot4(rq, rq) + dot4(r3, r3);
            #pragma unroll
            for (int e = 0; e < CHUNK; ++e) {
                const float4 h4 = *(const float4*)&h_lds[e][rbase + 4 * pg];
                acc[e] += h4.x * dot4(r0, t4[e]) + h4.y * dot4(r1, t4[e])
                        + h4.z * dot4(rq, t4[e]) + h4.w * dot4(r3, t4[e]);
            }
        }

        // reductions (slot-invariant trees -> scores bit-stable)
        #pragma unroll
        for (int off = 32; off >= 1; off >>= 1) r2 += __shfl_xor(r2, off);
        if (l == 0) r2_red[w] = r2;

        #pragma unroll
        for (int e = 0; e < CHUNK; ++e) {
            float v = acc[e];
            #pragma unroll
            for (int off = 32; off >= 1; off >>= 1) v += __shfl_xor(v, off);
            if (l == 0) red[w][e] = v;
        }
        __syncthreads();

        if (tid < e_cnt) {
            const float s  = red[0][tid] + red[1][tid] + red[2][tid] + red[3][tid];
            const int4 qd  = quad[start + tid];
            out[1 + qd.z] = s;
            const float d  = s - __int_as_float(qd.w);
            d2s[tid] = d * d;
        }
        __syncthreads();

        if (tid == 0) {
            float err = 0.f, ht = 0.f;
            for (int e = 0; e < e_cnt; ++e) { err += d2s[e]; ht += ht_red[e]; }
            const float r2t = r2_red[0] + r2_red[1] + r2_red[2] + r2_red[3];
            chunk_out[cid] = make_float4(err, ht, (float)e_cnt * r2t, 0.f);
        }
    }

    // ---- last-block loss reduction (order-fixed -> deterministic sum) ----
    __syncthreads();
    if (tid == 0) {
        __threadfence();                               // release chunk_out
        const int old = atomicAdd(done, 1);
        amlast = (old == MAXCHUNKS - 1) ? 1 : 0;
    }
    __syncthreads();
    if (amlast) {
        __threadfence();                               // acquire others' writes
        float err = 0.f, ht = 0.f, r2 = 0.f;
        for (int i = tid; i < MAXCHUNKS; i += 256) {
            const float4 c = chunk_out[i];
            err += c.x; ht += c.y; r2 += c.z;
        }
        #pragma unroll
        for (int off = 32; off >= 1; off >>= 1) {
            err += __shfl_down(err, off);
            ht  += __shfl_down(ht, off);
            r2  += __shfl_down(r2, off);
        }
        if ((tid & 63) == 0) {
            const int v = tid >> 6;
            red[0][v] = err; red[1][v] = ht; red[2][v] = r2;
        }
        __syncthreads();
        if (tid == 0) {
            err = red[0][0] + red[0][1] + red[0][2] + red[0][3];
            ht  = red[1][0] + red[1][1] + red[1][2] + red[1][3];
            r2  = red[2][0] + red[2][1] + red[2][2] + red[2][3];
            const float mse   = err / (float)BATCH;
            const float norms = (ht / ((float)BATCH * DIM)
                               + r2 / ((float)BATCH * (float)(DIM * DIM))) / 3.0f;
            out[0] = mse + ALPHA * norms;
        }
    }
}

extern "C" void kernel_launch(void* const* d_in, const int* in_sizes, int n_in,
                              void* d_out, int out_size, void* d_ws, size_t ws_size,
                              hipStream_t stream) {
    const int*   h_idx  = (const int*)d_in[0];
    const int*   r_idx  = (const int*)d_in[1];
    const int*   t_idx  = (const int*)d_in[2];
    const float* labels = (const float*)d_in[3];
    const float* ent_w  = (const float*)d_in[4];
    const float* rel_w  = (const float*)d_in[5];

    float* out = (float*)d_out;   // [0]=loss, [1..BATCH]=scores

    // workspace layout (~470 KB)
    char* ws = (char*)d_ws;
    int4*   quad       = (int4*)ws;             ws += BATCH * sizeof(int4);        // 256K
    int*    partialT   = (int*)ws;              ws += 512 * NHB * sizeof(int);     // 128K
    int4*   chunk_info = (int4*)ws;             ws += MAXCHUNKS * sizeof(int4);    // ~41K
    float4* chunk_out  = (float4*)ws;           ws += MAXCHUNKS * sizeof(float4);  // ~41K
    int*    done       = (int*)ws;

    hist_kernel<<<NHB, 256, 0, stream>>>(r_idx, partialT);
    scatter_kernel<<<NHB, 256, 0, stream>>>(r_idx, h_idx, t_idx, labels,
                                            partialT, quad, chunk_info, done);
    rescal_main_kernel<<<MAXCHUNKS, 256, 0, stream>>>(
        chunk_info, quad, ent_w, rel_w, out, chunk_out, done);
}

// Round 12
// 48.203 us; speedup vs baseline: 2.1236x; 2.1236x over previous
//
#include <hip/hip_runtime.h>

#define DIM       128
#define BATCH     16384
#define RELN      500
#define ALPHA     0.001f
#define CHUNK     8
#define MAXCHUNKS (BATCH / CHUNK + RELN)   // 2548 chunk slots (padded)
#define NHB       64                       // hist/scatter blocks (256 elems each)

__device__ __forceinline__ float dot4(float4 a, float4 b) {
    return a.x * b.x + a.y * b.y + a.z * b.z + a.w * b.w;
}

// ---------- K1: own-slice histogram -> BIN-MAJOR partials ----------
__global__ void __launch_bounds__(256) hist_kernel(
    const int* __restrict__ r_idx,
    int*       __restrict__ partialT)    // [512][NHB] bin-major
{
    __shared__ int cnt[512];
    const int tid = threadIdx.x;
    cnt[tid] = 0; cnt[tid + 256] = 0;
    __syncthreads();
    atomicAdd(&cnt[r_idx[blockIdx.x * 256 + tid]], 1);
    __syncthreads();
    partialT[tid * NHB + blockIdx.x]         = cnt[tid];
    partialT[(tid + 256) * NHB + blockIdx.x] = cnt[tid + 256];
}

// ---------- K2: scatter (redundant per-block scan, all LDS/regs) ----------
__global__ void __launch_bounds__(256) scatter_kernel(
    const int*   __restrict__ r_idx,
    const int*   __restrict__ h_idx,
    const int*   __restrict__ t_idx,
    const float* __restrict__ labels,
    const int*   __restrict__ partialT,   // [512][NHB]
    int4*        __restrict__ quad,       // [BATCH] (h, t, b, label_bits)
    int4*        __restrict__ chunk_info) // [MAXCHUNKS] (rel, start, e_cnt, 0)
{
    __shared__ int sc[512];
    __shared__ int boff[512];
    __shared__ int lcnt[512];
    const int tid = threadIdx.x;
    const int bid = blockIdx.x;

    // per-bin total + prefix(b < bid), contiguous int4 reads
    const int4* row0 = (const int4*)(partialT + tid * NHB);
    const int4* row1 = (const int4*)(partialT + (tid + 256) * NHB);
    int tot0 = 0, pre0 = 0, tot1 = 0, pre1 = 0;
    #pragma unroll
    for (int k = 0; k < 16; ++k) {
        const int4 v0 = row0[k];
        const int4 v1 = row1[k];
        tot0 += v0.x + v0.y + v0.z + v0.w;
        tot1 += v1.x + v1.y + v1.z + v1.w;
        const int b = 4 * k;
        pre0 += (b < bid ? v0.x : 0) + (b + 1 < bid ? v0.y : 0)
              + (b + 2 < bid ? v0.z : 0) + (b + 3 < bid ? v0.w : 0);
        pre1 += (b < bid ? v1.x : 0) + (b + 1 < bid ? v1.y : 0)
              + (b + 2 < bid ? v1.z : 0) + (b + 3 < bid ? v1.w : 0);
    }

    // 512-wide inclusive scan (2 elems/thread Hillis-Steele)
    sc[tid] = tot0; sc[tid + 256] = tot1;
    __syncthreads();
    for (int d = 1; d < 512; d <<= 1) {
        const int x0 = (tid >= d) ? sc[tid - d] : 0;
        const int x1 = (tid + 256 >= d) ? sc[tid + 256 - d] : 0;
        __syncthreads();
        sc[tid] += x0; sc[tid + 256] += x1;
        __syncthreads();
    }
    const int excl0 = sc[tid] - tot0;
    const int excl1 = sc[tid + 256] - tot1;
    boff[tid]       = excl0 + pre0;
    boff[tid + 256] = excl1 + pre1;
    lcnt[tid] = 0; lcnt[tid + 256] = 0;
    __syncthreads();

    // scatter own element
    {
        const int i   = bid * 256 + tid;
        const int r   = r_idx[i];
        const int pos = boff[r] + atomicAdd(&lcnt[r], 1);
        quad[pos] = make_int4(h_idx[i], t_idx[i], i, __float_as_int(labels[i]));
    }

    // block NHB-1: chunk_info (+ zero tail). Uniform branch; barriers OK.
    if (bid == NHB - 1) {
        const int nc0 = (tot0 + CHUNK - 1) / CHUNK;            // bins 0..255 < RELN
        const int nc1 = (tid + 256 < RELN) ? (tot1 + CHUNK - 1) / CHUNK : 0;
        __syncthreads();
        sc[tid] = nc0; sc[tid + 256] = nc1;
        __syncthreads();
        for (int d = 1; d < 512; d <<= 1) {
            const int x0 = (tid >= d) ? sc[tid - d] : 0;
            const int x1 = (tid + 256 >= d) ? sc[tid + 256 - d] : 0;
            __syncthreads();
            sc[tid] += x0; sc[tid + 256] += x1;
            __syncthreads();
        }
        const int cb0   = sc[tid] - nc0;
        const int cb1   = sc[tid + 256] - nc1;
        const int total = sc[511];
        for (int i = 0; i < nc0; ++i)
            chunk_info[cb0 + i] = make_int4(tid, excl0 + i * CHUNK,
                                            min(CHUNK, tot0 - i * CHUNK), 0);
        for (int i = 0; i < nc1; ++i)
            chunk_info[cb1 + i] = make_int4(tid + 256, excl1 + i * CHUNK,
                                            min(CHUNK, tot1 - i * CHUNK), 0);
        for (int p = total + tid; p < MAXCHUNKS; p += 256)
            chunk_info[p] = make_int4(0, 0, 0, 0);
    }
}

// ---------- K3: main — one block per chunk of 8; R streamed (R9's proven body) ----------
__global__ void __launch_bounds__(256) rescal_main_kernel(
    const int4*  __restrict__ chunk_info,
    const int4*  __restrict__ quad,
    const float* __restrict__ ent_w,
    const float* __restrict__ rel_w,
    float*       __restrict__ scores_out,   // d_out + 1
    float4*      __restrict__ chunk_out)    // [MAXCHUNKS] (errS, htS, cnt*r2, 0)
{
    // bijective XCD swizzle: consecutive cids (same relation) share an XCD L2
    const int bid = blockIdx.x;
    const int xcd = bid & 7;
    const int j   = bid >> 3;
    const int q   = MAXCHUNKS / 8;
    const int r_  = MAXCHUNKS % 8;
    const int cid = (xcd < r_ ? xcd * (q + 1) : r_ * (q + 1) + (xcd - r_) * q) + j;

    const int tid = threadIdx.x;

    const int4 ci    = chunk_info[cid];
    const int  rel   = ci.x;
    const int  start = ci.y;
    const int  e_cnt = ci.z;
    if (e_cnt == 0) {                        // padded slot: zero for final's pass
        if (tid == 0) chunk_out[cid] = make_float4(0.f, 0.f, 0.f, 0.f);
        return;
    }

    const int w   = tid >> 6;
    const int l   = tid & 63;
    const int hi  = l >> 5;
    const int c4  = l & 31;
    const int rbase = 32 * w + 16 * hi;

    __shared__ float t_lds[CHUNK][DIM];
    __shared__ float h_lds[CHUNK][DIM];
    __shared__ float red[4][CHUNK];
    __shared__ float ht_red[CHUNK];
    __shared__ float d2s[CHUNK];
    __shared__ float r2_red[4];

    // stage t, h (32 threads per element, 1 float4 each)
    const int eg   = tid >> 5;
    const int col4 = tid & 31;
    float4 tv4 = make_float4(0.f, 0.f, 0.f, 0.f);
    float4 hv4 = tv4;
    if (eg < e_cnt) {
        const int4 qd = quad[start + eg];
        hv4 = *(const float4*)(ent_w + (size_t)qd.x * DIM + col4 * 4);
        tv4 = *(const float4*)(ent_w + (size_t)qd.y * DIM + col4 * 4);
    }
    *(float4*)&t_lds[eg][col4 * 4] = tv4;
    *(float4*)&h_lds[eg][col4 * 4] = hv4;

    float htp = dot4(tv4, tv4) + dot4(hv4, hv4);
    #pragma unroll
    for (int off = 16; off >= 1; off >>= 1) htp += __shfl_xor(htp, off);
    if ((tid & 31) == 0) ht_red[eg] = htp;
    __syncthreads();

    // t fragments to registers (b128, conflict-free)
    float4 t4[CHUNK];
    #pragma unroll
    for (int e = 0; e < CHUNK; ++e)
        t4[e] = *(const float4*)&t_lds[e][c4 * 4];

    // stream R in 4-row groups (only 16 R-regs live)
    const float4* Rb = (const float4*)(rel_w + (size_t)rel * (DIM * DIM)
                                             + (size_t)rbase * DIM) + c4;
    float acc[CHUNK];
    #pragma unroll
    for (int e = 0; e < CHUNK; ++e) acc[e] = 0.f;
    float r2 = 0.f;

    #pragma unroll 1
    for (int pg = 0; pg < 4; ++pg) {
        const float4 r0 = Rb[(4 * pg + 0) * (DIM / 4)];
        const float4 r1 = Rb[(4 * pg + 1) * (DIM / 4)];
        const float4 rq = Rb[(4 * pg + 2) * (DIM / 4)];
        const float4 r3 = Rb[(4 * pg + 3) * (DIM / 4)];
        r2 += dot4(r0, r0) + dot4(r1, r1) + dot4(rq, rq) + dot4(r3, r3);
        #pragma unroll
        for (int e = 0; e < CHUNK; ++e) {
            const float4 h4 = *(const float4*)&h_lds[e][rbase + 4 * pg];
            acc[e] += h4.x * dot4(r0, t4[e]) + h4.y * dot4(r1, t4[e])
                    + h4.z * dot4(rq, t4[e]) + h4.w * dot4(r3, t4[e]);
        }
    }

    // reductions (slot-invariant trees -> scores bit-stable)
    #pragma unroll
    for (int off = 32; off >= 1; off >>= 1) r2 += __shfl_xor(r2, off);
    if (l == 0) r2_red[w] = r2;

    #pragma unroll
    for (int e = 0; e < CHUNK; ++e) {
        float v = acc[e];
        #pragma unroll
        for (int off = 32; off >= 1; off >>= 1) v += __shfl_xor(v, off);
        if (l == 0) red[w][e] = v;
    }
    __syncthreads();

    if (tid < e_cnt) {
        const float s  = red[0][tid] + red[1][tid] + red[2][tid] + red[3][tid];
        const int4 qd  = quad[start + tid];
        scores_out[qd.z] = s;
        const float d  = s - __int_as_float(qd.w);
        d2s[tid] = d * d;
    }
    __syncthreads();

    if (tid == 0) {
        float err = 0.f, ht = 0.f;
        for (int e = 0; e < e_cnt; ++e) { err += d2s[e]; ht += ht_red[e]; }
        const float r2t = r2_red[0] + r2_red[1] + r2_red[2] + r2_red[3];
        chunk_out[cid] = make_float4(err, ht, (float)e_cnt * r2t, 0.f);
    }
}

// ---------- K4: final — fixed-order reduction over full chunk_out -> loss ----------
__global__ void __launch_bounds__(256) final_kernel(
    const float4* __restrict__ chunk_out,
    float*        __restrict__ loss_out)
{
    const int tid = threadIdx.x;
    float err = 0.f, ht = 0.f, r2 = 0.f;
    for (int i = tid; i < MAXCHUNKS; i += 256) {
        const float4 c = chunk_out[i];
        err += c.x; ht += c.y; r2 += c.z;
    }
    __shared__ float re[4], rh[4], rr2[4];
    #pragma unroll
    for (int off = 32; off >= 1; off >>= 1) {
        err += __shfl_down(err, off);
        ht  += __shfl_down(ht, off);
        r2  += __shfl_down(r2, off);
    }
    if ((tid & 63) == 0) { const int v = tid >> 6; re[v] = err; rh[v] = ht; rr2[v] = r2; }
    __syncthreads();
    if (tid == 0) {
        err = re[0] + re[1] + re[2] + re[3];
        ht  = rh[0] + rh[1] + rh[2] + rh[3];
        r2  = rr2[0] + rr2[1] + rr2[2] + rr2[3];
        const float mse   = err / (float)BATCH;
        const float norms = (ht / ((float)BATCH * DIM)
                           + r2 / ((float)BATCH * (float)(DIM * DIM))) / 3.0f;
        loss_out[0] = mse + ALPHA * norms;
    }
}

extern "C" void kernel_launch(void* const* d_in, const int* in_sizes, int n_in,
                              void* d_out, int out_size, void* d_ws, size_t ws_size,
                              hipStream_t stream) {
    const int*   h_idx  = (const int*)d_in[0];
    const int*   r_idx  = (const int*)d_in[1];
    const int*   t_idx  = (const int*)d_in[2];
    const float* labels = (const float*)d_in[3];
    const float* ent_w  = (const float*)d_in[4];
    const float* rel_w  = (const float*)d_in[5];

    float* out = (float*)d_out;   // [0]=loss, [1..BATCH]=scores

    // workspace layout (~470 KB)
    char* ws = (char*)d_ws;
    int4*   quad       = (int4*)ws;             ws += BATCH * sizeof(int4);        // 256K
    int*    partialT   = (int*)ws;              ws += 512 * NHB * sizeof(int);     // 128K
    int4*   chunk_info = (int4*)ws;             ws += MAXCHUNKS * sizeof(int4);    // ~41K
    float4* chunk_out  = (float4*)ws;           // ~41K

    hist_kernel<<<NHB, 256, 0, stream>>>(r_idx, partialT);
    scatter_kernel<<<NHB, 256, 0, stream>>>(r_idx, h_idx, t_idx, labels,
                                            partialT, quad, chunk_info);
    rescal_main_kernel<<<MAXCHUNKS, 256, 0, stream>>>(
        chunk_info, quad, ent_w, rel_w, out + 1, chunk_out);
    final_kernel<<<1, 256, 0, stream>>>(chunk_out, out);
}